// Round 1
// 123.800 us; speedup vs baseline: 1.0967x; 1.0967x over previous
//
#include <hip/hip_runtime.h>
#include <hip/hip_bf16.h>
#include <math.h>

#define Hh 128   // hidden
#define Nn 32    // docs
#define Ll 128   // doc_len
#define W1S 384  // 3H
#define PAD 136  // bf16 elems per LDS row: 272B stride -> 2-way (free) frag reads

typedef __attribute__((ext_vector_type(8))) short short8;
typedef __attribute__((ext_vector_type(4))) float floatx4;

__device__ __forceinline__ unsigned short f2bf(float x) {
  __hip_bfloat16 h = __float2bfloat16(x);
  return __builtin_bit_cast(unsigned short, h);
}
__device__ __forceinline__ float bf2f(short s) {
  unsigned int u = ((unsigned int)(unsigned short)s) << 16;
  return __builtin_bit_cast(float, u);
}
__device__ __forceinline__ short8 pack8(float4 a, float4 b) {
  short8 r;
  r[0] = (short)f2bf(a.x); r[1] = (short)f2bf(a.y);
  r[2] = (short)f2bf(a.z); r[3] = (short)f2bf(a.w);
  r[4] = (short)f2bf(b.x); r[5] = (short)f2bf(b.y);
  r[6] = (short)f2bf(b.z); r[7] = (short)f2bf(b.w);
  return r;
}

// Grid 128: block b -> n = b>>2, which = (b>>1)&1 (0:Bt 1:Ct), mh = b&1 (M-half).
// scale folded at staging: docb[r][e] = bf16(doc[r][e] * scale[e]) -> no repack in GEMM.
// b1 folded into Bt here so k_main skips it.
__launch_bounds__(256, 2)
__global__ void k_prep(const float* __restrict__ wei, const int* __restrict__ wmask,
                       const float* __restrict__ doc, const float* __restrict__ q,
                       const float* __restrict__ W1, const float* __restrict__ b1,
                       float* __restrict__ Bt, float* __restrict__ Ct) {
  __shared__ __align__(16) short Wsb[Hh * PAD];   // bf16(W1b or W1c)
  __shared__ __align__(16) short docb[64 * PAD];  // bf16(doc * scale), this block's 64 rows
  __shared__ __align__(16) float red[2][Hh];
  __shared__ __align__(16) float scale[Hh];

  int b = blockIdx.x;
  int n = b >> 2, which = (b >> 1) & 1, mh = b & 1;
  int tid = threadIdx.x;
  const float* docn = doc + (size_t)n * Ll * Hh;
  int e8 = (tid & 15) * 8;  // constant across p since 256 % 16 == 0

  // issue this block's doc rows into registers early (overlaps wei latency)
  float4 dreg[4][2];
#pragma unroll
  for (int p = 0; p < 4; ++p) {
    int row = mh * 64 + p * 16 + (tid >> 4);
    const float4* dp = (const float4*)(docn + (size_t)row * Hh + e8);
    dreg[p][0] = dp[0]; dreg[p][1] = dp[1];
  }
  // stage W column block: which=0 -> W1b (+Hh), which=1 -> W1c (+2Hh)
#pragma unroll
  for (int p = 0; p < 8; ++p) {
    int row = p * 16 + (tid >> 4);
    const float4* wp = (const float4*)(W1 + (size_t)row * W1S + (which + 1) * Hh + e8);
    *(short8*)(Wsb + row * PAD + e8) = pack8(wp[0], wp[1]);
  }
  // scale vector: q row (which=1) or masked wei reduction (which=0)
  if (which == 1) {
    if (tid < Hh) scale[tid] = q[(n >> 3) * Hh + tid];
  } else {
    int e = tid & 127, halfl = tid >> 7;
    const float* wp = wei + (size_t)n * Ll * Hh + (size_t)halfl * 64 * Hh + e;
    const int* mp = wmask + n * Ll + halfl * 64;
    float a = 0.f;
#pragma unroll 16
    for (int l = 0; l < 64; ++l) a = fmaf((float)mp[l], wp[(size_t)l * Hh], a);
    red[halfl][e] = a;
  }
  __syncthreads();
  if (which == 0 && tid < Hh) scale[tid] = red[0][tid] + red[1][tid];
  __syncthreads();

  // docb = bf16(doc * scale)
  {
    float s[8];
#pragma unroll
    for (int i = 0; i < 8; ++i) s[i] = scale[e8 + i];
#pragma unroll
    for (int p = 0; p < 4; ++p) {
      int r = p * 16 + (tid >> 4);
      float4 a = dreg[p][0], bq = dreg[p][1];
      a.x *= s[0]; a.y *= s[1]; a.z *= s[2]; a.w *= s[3];
      bq.x *= s[4]; bq.y *= s[5]; bq.z *= s[6]; bq.w *= s[7];
      *(short8*)(docb + r * PAD + e8) = pack8(a, bq);
    }
  }
  __syncthreads();

  int lane = tid & 63, w = tid >> 6;        // 4 waves x 16 rows
  int l15 = lane & 15, quad = lane >> 4;
  floatx4 acc[8];
#pragma unroll
  for (int nt = 0; nt < 8; ++nt) acc[nt] = (floatx4){0.f, 0.f, 0.f, 0.f};
#pragma unroll
  for (int c = 0; c < 4; ++c) {
    int eo = c * 32 + quad * 8;
    short8 af = *(const short8*)(docb + (w * 16 + l15) * PAD + eo);
    short8 bfr[8];
#pragma unroll
    for (int nt = 0; nt < 8; ++nt)
      bfr[nt] = *(const short8*)(Wsb + (nt * 16 + l15) * PAD + eo);
#pragma unroll
    for (int nt = 0; nt < 8; ++nt)
      acc[nt] = __builtin_amdgcn_mfma_f32_16x16x32_bf16(af, bfr[nt], acc[nt], 0, 0, 0);
  }

  float* outp = (which ? Ct : Bt) + (size_t)n * Ll * Hh;
#pragma unroll
  for (int nt = 0; nt < 8; ++nt) {
    int g = nt * 16 + l15;
    float badd = which ? 0.f : b1[g];
#pragma unroll
    for (int r = 0; r < 4; ++r) {
      int k = mh * 64 + w * 16 + quad * 4 + r;
      outp[(size_t)k * Hh + g] = acc[nt][r] + badd;
    }
  }
}

// One block per (n,j), XCD-swizzled: n = bid & 31 so all j-blocks of n share XCD n%8.
// 512 threads (8 waves x 16 k-rows): same LDS -> 2 blocks/CU but 16 waves/CU (2x TLP).
__launch_bounds__(512, 4)
__global__ void k_main(const float* __restrict__ doc, const int* __restrict__ dmask,
                       const float* __restrict__ W1,
                       const float* __restrict__ w2, const float* __restrict__ b2,
                       const float* __restrict__ Bt, const float* __restrict__ Ct,
                       float* __restrict__ out) {
  __shared__ __align__(16) short As[Hh * PAD];  // As[g][e] = bf16(W1a)
  __shared__ __align__(16) short Bs[Hh * PAD];  // Bs[k][e] = bf16(doc*dj)
  __shared__ __align__(16) float sc[Ll];
  __shared__ __align__(16) float scw[Ll];

  int bid = blockIdx.x;
  int n = bid & 31, j = bid >> 5;   // XCD-locality swizzle
  int tid = threadIdx.x;
  const float* docn = doc + (size_t)n * Ll * Hh;
  size_t orow = ((size_t)n * Ll + j) * Hh;

  if (dmask[n * Ll + j] == 0) {     // fully-masked row -> exact zeros (~50% of blocks)
    if (tid < Hh) out[orow + tid] = 0.f;
    return;
  }

  int e8 = (tid & 15) * 8;  // constant across p since 512 % 16 == 0
  const float4* jp = (const float4*)(docn + (size_t)j * Hh + e8);
  float4 j0 = jp[0], j1 = jp[1];
#pragma unroll
  for (int p = 0; p < 4; ++p) {
    int row = p * 32 + (tid >> 4);
    const float4* wp = (const float4*)(W1 + (size_t)row * W1S + e8);
    *(short8*)(As + row * PAD + e8) = pack8(wp[0], wp[1]);
    const float4* dp = (const float4*)(docn + (size_t)row * Hh + e8);
    float4 d0 = dp[0], d1 = dp[1];
    d0.x *= j0.x; d0.y *= j0.y; d0.z *= j0.z; d0.w *= j0.w;
    d1.x *= j1.x; d1.y *= j1.y; d1.z *= j1.z; d1.w *= j1.w;
    *(short8*)(Bs + row * PAD + e8) = pack8(d0, d1);
  }
  __syncthreads();

  int lane = tid & 63, w = tid >> 6;     // w in 0..7, 16 k-rows per wave
  int l15 = lane & 15, quad = lane >> 4;

  // hoist epilogue operands above the GEMM so the L2 loads fly under MFMA
  const float c2 = 2.885390081777927f;  // 2*log2(e)
  float bbc[8], w2r[8];
  const float* btrow = Bt + orow;
#pragma unroll
  for (int nt = 0; nt < 8; ++nt) {
    int g = nt * 16 + l15;
    bbc[nt] = btrow[g] * c2;             // b1 already folded into Bt by k_prep
    w2r[nt] = w2[g];
  }

  floatx4 acc[8];
#pragma unroll
  for (int nt = 0; nt < 8; ++nt) acc[nt] = (floatx4){0.f, 0.f, 0.f, 0.f};
#pragma unroll
  for (int e0 = 0; e0 < Hh; e0 += 32) {
    int eo = e0 + quad * 8;
    short8 af = *(const short8*)(Bs + (w * 16 + l15) * PAD + eo);
    short8 bfr[8];
#pragma unroll
    for (int nt = 0; nt < 8; ++nt)
      bfr[nt] = *(const short8*)(As + (nt * 16 + l15) * PAD + eo);
#pragma unroll
    for (int nt = 0; nt < 8; ++nt)
      acc[nt] = __builtin_amdgcn_mfma_f32_16x16x32_bf16(af, bfr[nt], acc[nt], 0, 0, 0);
  }

  // epilogue: tanh(acc + Ct[k,g] + Bt[j,g] + b1[g]) . w2  -> sc[k]
  const float* ctn = Ct + (size_t)n * Ll * Hh;
#pragma unroll
  for (int r = 0; r < 4; ++r) {
    int k = w * 16 + quad * 4 + r;
    const float* ctp = ctn + (size_t)k * Hh + l15;
    float p = 0.f;
#pragma unroll
    for (int nt = 0; nt < 8; ++nt) {
      float s = acc[nt][r] + ctp[nt * 16];
      float a2 = fmaf(s, c2, bbc[nt]);
      float e = exp2f(a2);
      float th = fmaf(-2.f, __builtin_amdgcn_rcpf(e + 1.f), 1.f);
      p = fmaf(th, w2r[nt], p);
    }
    p += __shfl_xor(p, 1);
    p += __shfl_xor(p, 2);
    p += __shfl_xor(p, 4);
    p += __shfl_xor(p, 8);
    if (l15 == 0) sc[k] = p;
  }
  __syncthreads();

  // redundant per-wave masked softmax (no extra barriers)
  {
    float b2v = b2[0];
    const float inv = 0.088388347648318447f;  // 1/sqrt(128)
    const int* dmn = dmask + n * Ll;
    int m0 = dmn[lane], m1 = dmn[lane + 64];
    float s0 = (sc[lane] + b2v) * inv;
    float s1 = (sc[lane + 64] + b2v) * inv;
    s0 = m0 ? s0 : -1e9f;
    s1 = m1 ? s1 : -1e9f;
    float mx = fmaxf(s0, s1);
#pragma unroll
    for (int off = 32; off; off >>= 1) mx = fmaxf(mx, __shfl_xor(mx, off));
    float ex0 = __expf(s0 - mx), ex1 = __expf(s1 - mx);
    float sm = ex0 + ex1;
#pragma unroll
    for (int off = 32; off; off >>= 1) sm += __shfl_xor(sm, off);
    float rden = 1.f / sm;
    scw[lane] = m0 ? ex0 * rden : 0.f;       // all 8 waves write identical values
    scw[lane + 64] = m1 ? ex1 * rden : 0.f;
  }
  __syncthreads();

  // out[j,h] = sum_k w[k] * doc[n,k,h] ; 4-way k-split across the 512 threads
  float* ored = (float*)As;  // As dead after GEMM
  int halfk = tid >> 7, h = tid & 127;
  const float* dbase = docn + (size_t)halfk * 32 * Hh + h;
  float o = 0.f;
#pragma unroll 8
  for (int kk = 0; kk < 32; ++kk)
    o = fmaf(scw[halfk * 32 + kk], dbase[(size_t)kk * Hh], o);
  ored[halfk * Hh + h] = o;
  __syncthreads();
  if (tid < Ll)
    out[orow + tid] = ored[tid] + ored[Hh + tid] + ored[2 * Hh + tid] + ored[3 * Hh + tid];
}

extern "C" void kernel_launch(void* const* d_in, const int* in_sizes, int n_in,
                              void* d_out, int out_size, void* d_ws, size_t ws_size,
                              hipStream_t stream) {
  const float* wei   = (const float*)d_in[0];
  const int*   wmask = (const int*)d_in[1];
  const float* doc   = (const float*)d_in[2];
  const int*   dmask = (const int*)d_in[3];
  const float* q     = (const float*)d_in[4];
  const float* W1    = (const float*)d_in[5];
  const float* b1    = (const float*)d_in[6];
  const float* w2    = (const float*)d_in[7];
  const float* b2    = (const float*)d_in[8];
  float* out = (float*)d_out;

  float* ws = (float*)d_ws;
  float* Bt = ws;                           // N*L*H (b1 folded in)
  float* Ct = Bt + (size_t)Nn * Ll * Hh;    // N*L*H   (total 4.19 MB, <= round-1 usage)

  k_prep<<<Nn * 4, 256, 0, stream>>>(wei, wmask, doc, q, W1, b1, Bt, Ct);
  k_main<<<Nn * Ll, 512, 0, stream>>>(doc, dmask, W1, w2, b2, Bt, Ct, out);
}